// Round 7
// baseline (22097.983 us; speedup 1.0000x reference)
//
#include <hip/hip_runtime.h>
#include <math.h>

typedef unsigned short u16;
typedef __attribute__((ext_vector_type(8))) short short8;
typedef __attribute__((ext_vector_type(4))) float f32x4;

__device__ __forceinline__ float sigm(float x) { return 1.0f / (1.0f + expf(-x)); }

__device__ __forceinline__ u16 f2bf(float x) {
    union { float f; unsigned u; } v; v.f = x;
    unsigned r = v.u + 0x7fffu + ((v.u >> 16) & 1u);
    return (u16)(r >> 16);
}
__device__ __forceinline__ float bf2f(u16 h) {
    union { unsigned u; float f; } v; v.u = ((unsigned)h) << 16;
    return v.f;
}
__device__ __forceinline__ f32x4 mfma16(short8 a, short8 b, f32x4 c) {
    return __builtin_amdgcn_mfma_f32_16x16x32_bf16(a, b, c, 0, 0, 0);
}

// ---------------------------------------------------------------------------
// Packed layouts (per bf16 plane), all tiles 1 KB = 64 lanes x 16 B:
//  A-pack  (m in [0,128), k in [0,2048)):
//    elem = (k>>5)*4096 + (m>>4)*512 + ((k>>3)&3)*128 + (m&15)*8 + (k&7)
//  W-pack  (n16 = col'>>4, kg = k-slice):  tile base elem = (n16*NKG + kg)*512
//    within tile: ((k>>3)&3)*128 + (col'&15)*8 + (k&7)
//  -> every K-loop load is global_load_dwordx4 at base + lane*16 (coalesced).
// ---------------------------------------------------------------------------

// k_step: ONE kernel per timestep. NO __syncthreads anywhere.
// Grid 512 blocks x 256 thr (2 blocks/CU). bid: rh=(bid>>3)&1,
// id=((bid>>4)<<3)|(bid&7): dir=id&1, cg=id>>1 (row-half pairs share XCD).
// Block 64 rows x 32 cols; wave (wr=w&1, wc=w>>1) = 32 rows x 16 cols.
// K-loop: 32-K slices, 4 named register sets, prefetch distance 3.
#define LOADKG(c_, S)                                                         \
    do {                                                                      \
        const size_t ao_ = (size_t)(c_) * 4096;                               \
        aH[S][0] = *(const short8*)(abh + ao_);                               \
        aH[S][1] = *(const short8*)(abh + ao_ + 512);                         \
        aL[S][0] = *(const short8*)(abl + ao_);                               \
        aL[S][1] = *(const short8*)(abl + ao_ + 512);                         \
        const size_t bo_ = (size_t)(c_) * 512;                                \
        bH[S] = *(const short8*)(bbh + bo_);                                  \
        bL[S] = *(const short8*)(bbl + bo_);                                  \
    } while (0)

#define COMPUTE(S, c_)                                                        \
    do {                                                                      \
        acc0 = mfma16(aH[S][0], bH[S], acc0);                                 \
        acc1 = mfma16(aH[S][1], bH[S], acc1);                                 \
        acc0 = mfma16(aL[S][0], bH[S], acc0);                                 \
        acc1 = mfma16(aL[S][1], bH[S], acc1);                                 \
        acc0 = mfma16(aH[S][0], bL[S], acc0);                                 \
        acc1 = mfma16(aH[S][1], bL[S], acc1);                                 \
        if (fc1w) {                                                           \
            const int kb_ = (akg0 + (c_)) * 32 + quad * 8;                    \
            const f32x4 w0_ = *(const f32x4*)(Wfc1 + kb_);                    \
            const f32x4 w1_ = *(const f32x4*)(Wfc1 + kb_ + 4);                \
            _Pragma("unroll") for (int mt_ = 0; mt_ < 2; ++mt_) {             \
                const short8 hv_ = aH[S][mt_];                                \
                const short8 lv_ = aL[S][mt_];                                \
                _Pragma("unroll") for (int e_ = 0; e_ < 8; ++e_) {            \
                    const float v_ = bf2f((u16)hv_[e_]) + bf2f((u16)lv_[e_]); \
                    const float wv_ = (e_ < 4) ? w0_[e_] : w1_[e_ - 4];       \
                    fsum[mt_] = fmaf(fmaxf(v_, 0.0f), wv_, fsum[mt_]);        \
                }                                                             \
            }                                                                 \
        }                                                                     \
    } while (0)

__global__ __launch_bounds__(256, 2) void k_step(
    const u16* __restrict__ Ah, const u16* __restrict__ Al,
    u16* __restrict__ NAh, u16* __restrict__ NAl,
    const u16* __restrict__ BFh, const u16* __restrict__ BFl,
    const u16* __restrict__ BBh, const u16* __restrict__ BBl,
    int nkg_f, int nkg_b, int akg0_b,
    const float* __restrict__ BR, float* __restrict__ CF, float* __restrict__ CB,
    const float* __restrict__ Wfc1, const float* __restrict__ bfc1,
    float* __restrict__ out, int T, int t)
{
    __shared__ __align__(16) char sm[9216];   // 4 x 2304 B per-wave epi scratch

    const int tid = threadIdx.x, bid = blockIdx.x;
    const int w = tid >> 6, lane = tid & 63, l15 = lane & 15, quad = lane >> 4;
    const int rh = (bid >> 3) & 1;
    const int id = ((bid >> 4) << 3) | (bid & 7);   // [0,256)
    const int dir = id & 1;
    const int cg = id >> 1;                          // [0,128) col-group of 32
    const int wr = w & 1, wc = w >> 1;
    const int r0 = rh * 64 + wr * 32;                // wave's 32 rows
    const int n16 = cg * 2 + wc;                     // [0,256) per dir
    const int nkg = dir ? nkg_b : nkg_f;
    const int akg0 = dir ? akg0_b : 0;
    const u16* Bh = dir ? BBh : BFh;
    const u16* Bl = dir ? BBl : BFl;

    const bool fc1w = (t > 0) && (dir == 0) && (cg == 0) && (wc == 0);

    const int mt0 = r0 >> 4;
    const u16* abh = Ah + (size_t)akg0 * 4096 + mt0 * 512 + lane * 8;
    const u16* abl = Al + (size_t)akg0 * 4096 + mt0 * 512 + lane * 8;
    const u16* bbh = Bh + (size_t)n16 * nkg * 512 + lane * 8;
    const u16* bbl = Bl + (size_t)n16 * nkg * 512 + lane * 8;

    f32x4 acc0 = {}, acc1 = {};
    short8 aH[4][2], aL[4][2], bH[4], bL[4];   // literal set indices only
    float fsum[2] = {0.0f, 0.0f};

    LOADKG(0, 0);
    LOADKG(1, 1);
    LOADKG(2, 2);
    for (int c = 0; c < nkg; c += 4) {
        if (c + 3 < nkg) LOADKG(c + 3, 3);
        COMPUTE(0, c);
        if (c + 4 < nkg) LOADKG(c + 4, 0);
        COMPUTE(1, c + 1);
        if (c + 5 < nkg) LOADKG(c + 5, 1);
        COMPUTE(2, c + 2);
        if (c + 6 < nkg) LOADKG(c + 6, 2);
        COMPUTE(3, c + 3);
    }

    // fc1 reduce + plain store (no atomics, no barrier)
    if (fc1w) {
#pragma unroll
        for (int mt = 0; mt < 2; ++mt) {
            float v = fsum[mt];
            v += __shfl_xor(v, 16);
            v += __shfl_xor(v, 32);
            if (lane < 16)
                out[(size_t)(r0 + mt * 16 + l15) * T + (t - 1)] = v + bfc1[0];
        }
    }

    // epilogue: per-wave private LDS transpose (32 rows x 16 cols, stride 72 B)
    char* zb = sm + w * 2304;
#pragma unroll
    for (int mt = 0; mt < 2; ++mt) {
        const f32x4 a = mt ? acc1 : acc0;
#pragma unroll
        for (int r = 0; r < 4; ++r)
            *(float*)(zb + (mt * 16 + quad * 4 + r) * 72 + l15 * 4) = a[r];
    }
    float* C = dir ? CB : CF;
#pragma unroll
    for (int p = 0; p < 2; ++p) {
        const int idx = p * 64 + lane;       // 128 (m,u) pairs per wave
        const int ml = idx >> 2;             // 0..31
        const int ul = idx & 3;              // 0..3
        const f32x4 z = *(const f32x4*)(zb + ml * 72 + ul * 16);
        const int colb = dir * 4096 + n16 * 16 + ul * 4;
        const f32x4 b4 = *(const f32x4*)(BR + colb);
        const float zi = z[0] + b4[0], zf = z[1] + b4[1];
        const float zg = z[2] + b4[2], zo = z[3] + b4[3];
        const int u = n16 * 4 + ul;          // unit within direction
        const int m = r0 + ml;
        const size_t cidx = (size_t)m * 1024 + u;
        const float cold = C[cidx];
        const float c2 = sigm(zf) * cold + sigm(zi) * tanhf(zg);
        const float h2 = sigm(zo) * tanhf(c2);
        C[cidx] = c2;
        const int kA = dir * 1024 + u;
        const size_t ia = (size_t)(kA >> 5) * 4096 + (m >> 4) * 512
                        + ((kA >> 3) & 3) * 128 + (m & 15) * 8 + (kA & 7);
        const u16 hh = f2bf(h2);
        NAh[ia] = hh;
        NAl[ia] = f2bf(h2 - bf2f(hh));
    }
}

// ---------------------------------------------------------------------------
// k_tail: out[:, T-1] from final A pack. 128 blocks (one per row).
// ---------------------------------------------------------------------------
__global__ __launch_bounds__(256) void k_tail(
    const u16* __restrict__ Ah, const u16* __restrict__ Al,
    const float* __restrict__ Wfc1, const float* __restrict__ bfc1,
    float* __restrict__ out, int T)
{
    __shared__ float red[256];
    const int m = blockIdx.x, tid = threadIdx.x;
    const size_t base = (size_t)(tid >> 2) * 4096 + (m >> 4) * 512
                      + (tid & 3) * 128 + (m & 15) * 8;
    const short8 hv = *(const short8*)(Ah + base);
    const short8 lv = *(const short8*)(Al + base);
    float s = 0.0f;
#pragma unroll
    for (int e = 0; e < 8; ++e) {
        const float v = bf2f((u16)hv[e]) + bf2f((u16)lv[e]);
        s = fmaf(fmaxf(v, 0.0f), Wfc1[tid * 8 + e], s);
    }
    red[tid] = s;
    __syncthreads();
    for (int off = 128; off > 0; off >>= 1) {
        if (tid < off) red[tid] += red[tid + off];
        __syncthreads();
    }
    if (tid == 0) out[(size_t)m * T + T - 1] = red[0] + bfc1[0];
}

// ---------------------------------------------------------------------------
// k_fold: fold = (Wih' @ WoT^T)[col'][j] (+ Whh_b for bwd cols), written into
// packed PF (fwd, kg 32..63) / PB (bwd, kg 0..31).
// ---------------------------------------------------------------------------
__global__ __launch_bounds__(256, 1) void k_fold(
    const u16* __restrict__ AH, const u16* __restrict__ AL,   // Wih' 8192x512
    const u16* __restrict__ BH, const u16* __restrict__ BL,   // WoT 1024x512
    const float* __restrict__ Whh_b,
    u16* __restrict__ PFH, u16* __restrict__ PFL,
    u16* __restrict__ PBH, u16* __restrict__ PBL)
{
    const int tid = threadIdx.x, bid = blockIdx.x;
    const int w = tid >> 6, lane = tid & 63, l15 = lane & 15, quad = lane >> 4;
    const int bm = bid >> 4, bn = bid & 15;
    const int ar0 = bm * 64 + (w & 1) * 32;
    const int br0 = bn * 64 + (w >> 1) * 32;
    f32x4 acc[2][2] = {};
    for (int k0 = 0; k0 < 512; k0 += 32) {
        short8 a_h[2], a_l[2], b_h[2], b_l[2];
#pragma unroll
        for (int mt = 0; mt < 2; ++mt) {
            const size_t o = (size_t)(ar0 + mt * 16 + l15) * 512 + k0 + quad * 8;
            a_h[mt] = *(const short8*)(AH + o);
            a_l[mt] = *(const short8*)(AL + o);
        }
#pragma unroll
        for (int nt = 0; nt < 2; ++nt) {
            const size_t o = (size_t)(br0 + nt * 16 + l15) * 512 + k0 + quad * 8;
            b_h[nt] = *(const short8*)(BH + o);
            b_l[nt] = *(const short8*)(BL + o);
        }
#pragma unroll
        for (int mt = 0; mt < 2; ++mt)
#pragma unroll
            for (int nt = 0; nt < 2; ++nt) {
                acc[mt][nt] = mfma16(a_h[mt], b_h[nt], acc[mt][nt]);
                acc[mt][nt] = mfma16(a_l[mt], b_h[nt], acc[mt][nt]);
                acc[mt][nt] = mfma16(a_h[mt], b_l[nt], acc[mt][nt]);
            }
    }
#pragma unroll
    for (int mt = 0; mt < 2; ++mt)
#pragma unroll
        for (int nt = 0; nt < 2; ++nt)
#pragma unroll
            for (int r = 0; r < 4; ++r) {
                const int row = ar0 + mt * 16 + quad * 4 + r;   // col' [0,8192)
                const int j = br0 + nt * 16 + l15;              // [0,1024)
                float v = acc[mt][nt][r];
                if (row >= 4096)
                    v += Whh_b[(size_t)((row & 3) * 1024 + ((row & 4095) >> 2)) * 1024 + j];
                const u16 hh = f2bf(v);
                const u16 ll = f2bf(v - bf2f(hh));
                if (row < 4096) {
                    const size_t ix = (size_t)((row >> 4) * 64 + 32 + (j >> 5)) * 512
                                    + ((j >> 3) & 3) * 128 + (row & 15) * 8 + (j & 7);
                    PFH[ix] = hh; PFL[ix] = ll;
                } else {
                    const int rl = row - 4096;
                    const size_t ix = (size_t)((rl >> 4) * 32 + (j >> 5)) * 512
                                    + ((j >> 3) & 3) * 128 + (rl & 15) * 8 + (j & 7);
                    PBH[ix] = hh; PBL[ix] = ll;
                }
            }
}

// ---------------------------------------------------------------------------
// k_prep: Wih' linear hi/lo, WoT hi/lo, BR0/BR1, A0 pack, out init,
//         Whh_f -> PF pack (kg 0..31), Wih' -> P0 pack (K=512, both dirs).
// ---------------------------------------------------------------------------
__global__ __launch_bounds__(256) void k_prep(
    const float* __restrict__ dec,
    const float* __restrict__ Wih_f, const float* __restrict__ Whh_f,
    const float* __restrict__ b_f, const float* __restrict__ Wih_b,
    const float* __restrict__ b_b, const float* __restrict__ W_out,
    const float* __restrict__ b_out, const float* __restrict__ b_fc1,
    u16* __restrict__ WihH, u16* __restrict__ WihL,
    u16* __restrict__ WoTH, u16* __restrict__ WoTL,
    float* __restrict__ BR0, float* __restrict__ BR1,
    u16* __restrict__ A0h, u16* __restrict__ A0l,
    u16* __restrict__ PFH, u16* __restrict__ PFL,
    u16* __restrict__ P0H, u16* __restrict__ P0L,
    float* __restrict__ out, int out_size)
{
    const int t = blockIdx.x * 256 + threadIdx.x;
    if (t < 524288) {                       // Wih' linear (gate-interleaved cols)
        const int colp = t >> 6, kb = (t & 63) * 8;
        const int dir = colp >> 12, u = (colp & 4095) >> 2, g = colp & 3;
        const float* src = (dir ? Wih_b : Wih_f) + (size_t)(g * 1024 + u) * 512 + kb;
        const size_t d = (size_t)colp * 512 + kb;
#pragma unroll
        for (int j = 0; j < 8; ++j) {
            const float v = src[j];
            const u16 hh = f2bf(v);
            WihH[d + j] = hh; WihL[d + j] = f2bf(v - bf2f(hh));
        }
    } else if (t < 589824) {                // WoT[j][l] = W_out[l][j]
        const int i = t - 524288, jc = i >> 6, lb = (i & 63) * 8;
#pragma unroll
        for (int jj = 0; jj < 8; ++jj) {
            const float v = W_out[(size_t)(lb + jj) * 1024 + jc];
            const size_t d = (size_t)jc * 512 + lb + jj;
            const u16 hh = f2bf(v);
            WoTH[d] = hh; WoTL[d] = f2bf(v - bf2f(hh));
        }
    } else if (t < 598016) {                // biases
        const int colp = t - 589824;
        const int dir = colp >> 12, u = (colp & 4095) >> 2, g = colp & 3;
        const float* Wih = dir ? Wih_b : Wih_f;
        const float s = (dir ? b_b : b_f)[g * 1024 + u];
        BR0[colp] = s;
        float dot = 0.0f;
        for (int l = 0; l < 512; ++l)
            dot += Wih[(size_t)(g * 1024 + u) * 512 + l] * b_out[l];
        BR1[colp] = s + dot;
    } else if (t < 606208) {                // A0 pack = dec (k in [0,512))
        const int i = t - 598016, m = i >> 6, kb = (i & 63) * 8;
        const size_t ia = (size_t)(kb >> 5) * 4096 + (m >> 4) * 512
                        + ((kb >> 3) & 3) * 128 + (m & 15) * 8;
#pragma unroll
        for (int j = 0; j < 8; ++j) {
            const float v = dec[(size_t)m * 512 + kb + j];
            const u16 hh = f2bf(v);
            A0h[ia + j] = hh; A0l[ia + j] = f2bf(v - bf2f(hh));
        }
    } else if (t < 614400) {                // out init = b_fc1 (safety net)
        const int base = (t - 606208) * 8;
        const float b0 = b_fc1[0];
#pragma unroll
        for (int j = 0; j < 8; ++j)
            if (base + j < out_size) out[base + j] = b0;
    } else if (t < 1138688) {               // Whh_f -> PF pack (fwd, kg 0..31)
        const int i = t - 614400, colp = i >> 7, kb = (i & 127) * 8;
        const int u = colp >> 2, g = colp & 3;
        const float* src = Whh_f + (size_t)(g * 1024 + u) * 1024 + kb;
        const size_t ix = (size_t)((colp >> 4) * 64 + (kb >> 5)) * 512
                        + ((kb >> 3) & 3) * 128 + (colp & 15) * 8;
#pragma unroll
        for (int j = 0; j < 8; ++j) {
            const float v = src[j];
            const u16 hh = f2bf(v);
            PFH[ix + j] = hh; PFL[ix + j] = f2bf(v - bf2f(hh));
        }
    } else {                                // Wih' -> P0 pack (K=512, all cols')
        const int i = t - 1138688, colp = i >> 6, kb = (i & 63) * 8;
        const int dir = colp >> 12, u = (colp & 4095) >> 2, g = colp & 3;
        const float* src = (dir ? Wih_b : Wih_f) + (size_t)(g * 1024 + u) * 512 + kb;
        const size_t ix = (size_t)((colp >> 4) * 16 + (kb >> 5)) * 512
                        + ((kb >> 3) & 3) * 128 + (colp & 15) * 8;
#pragma unroll
        for (int j = 0; j < 8; ++j) {
            const float v = src[j];
            const u16 hh = f2bf(v);
            P0H[ix + j] = hh; P0L[ix + j] = f2bf(v - bf2f(hh));
        }
    }
}

// ---------------------------------------------------------------------------
// ws layout (bytes):
//  0          PFH 16,777,216   (fwd pack, 256 n16 x 64 kg x 1 KB)
//  16777216   PFL 16,777,216
//  33554432   PBH  8,388,608   (bwd pack, 256 n16 x 32 kg)
//  41943040   PBL  8,388,608
//  50331648   P0H  8,388,608   (t=0 pack, 512 n16 x 16 kg)
//  58720256   P0L  8,388,608
//  67108864   WihH 8,388,608   (linear, k_fold input)
//  75497472   WihL 8,388,608
//  83886080   WoTH 1,048,576
//  84934656   WoTL 1,048,576
//  85983232   A0h/A0l/A1h/A1l 4 x 524,288 (A pack)
//  88080384   CF/CB 2 x 524,288 (fp32, zeroed)
//  89128960   BR0/BR1 2 x 32,768
// ---------------------------------------------------------------------------
extern "C" void kernel_launch(void* const* d_in, const int* in_sizes, int n_in,
                              void* d_out, int out_size, void* d_ws, size_t ws_size,
                              hipStream_t stream) {
    const float* dec   = (const float*)d_in[0];
    const float* Wih_f = (const float*)d_in[2];
    const float* Whh_f = (const float*)d_in[3];
    const float* b_f   = (const float*)d_in[4];
    const float* Wih_b = (const float*)d_in[5];
    const float* Whh_b = (const float*)d_in[6];
    const float* b_b   = (const float*)d_in[7];
    const float* W_out = (const float*)d_in[8];
    const float* b_out = (const float*)d_in[9];
    const float* W_fc1 = (const float*)d_in[10];
    const float* b_fc1 = (const float*)d_in[11];
    float* out = (float*)d_out;

    char* ws = (char*)d_ws;
    u16* PFH  = (u16*)(ws);
    u16* PFL  = (u16*)(ws + 16777216);
    u16* PBH  = (u16*)(ws + 33554432);
    u16* PBL  = (u16*)(ws + 41943040);
    u16* P0H  = (u16*)(ws + 50331648);
    u16* P0L  = (u16*)(ws + 58720256);
    u16* WihH = (u16*)(ws + 67108864);
    u16* WihL = (u16*)(ws + 75497472);
    u16* WoTH = (u16*)(ws + 83886080);
    u16* WoTL = (u16*)(ws + 84934656);
    u16* A0h  = (u16*)(ws + 85983232);
    u16* A0l  = (u16*)(ws + 86507520);
    u16* A1h  = (u16*)(ws + 87031808);
    u16* A1l  = (u16*)(ws + 87556096);
    float* CF  = (float*)(ws + 88080384);
    float* CB  = (float*)(ws + 88604672);
    float* BR0 = (float*)(ws + 89128960);
    float* BR1 = (float*)(ws + 89161728);

    k_prep<<<6496, 256, 0, stream>>>(dec, Wih_f, Whh_f, b_f, Wih_b, b_b,
                                     W_out, b_out, b_fc1,
                                     WihH, WihL, WoTH, WoTL, BR0, BR1,
                                     A0h, A0l, PFH, PFL, P0H, P0L, out, out_size);
    k_fold<<<2048, 256, 0, stream>>>(WihH, WihL, WoTH, WoTL, Whh_b,
                                     PFH, PFL, PBH, PBL);
    hipMemsetAsync(CF, 0, 1048576, stream);   // CF + CB contiguous

    const int T = out_size / 128;
    u16* Abh[2] = {A0h, A1h};
    u16* Abl[2] = {A0l, A1l};
    for (int t = 0; t < T; ++t) {
        const int in = t & 1, nx = in ^ 1;
        if (t == 0) {
            k_step<<<512, 256, 0, stream>>>(A0h, A0l, A1h, A1l,
                                            P0H, P0L, P0H + 2097152, P0L + 2097152,
                                            16, 16, 0,
                                            BR0, CF, CB, W_fc1, b_fc1, out, T, 0);
        } else {
            k_step<<<512, 256, 0, stream>>>(Abh[in], Abl[in], Abh[nx], Abl[nx],
                                            PFH, PFL, PBH, PBL,
                                            64, 32, 32,
                                            BR1, CF, CB, W_fc1, b_fc1, out, T, t);
        }
    }
    k_tail<<<128, 256, 0, stream>>>(Abh[T & 1], Abl[T & 1], W_fc1, b_fc1, out, T);
}